// Round 1
// baseline (156.203 us; speedup 1.0000x reference)
//
#include <hip/hip_runtime.h>

// ---------------------------------------------------------------------------
// DSTDGC: out[n,t,i,o] = sum_j adjf[n,t,i,j] * xf[n,t,j,o]
//   adjf = alpha*( sum_k w_rm[t,k]*tanh(m1[n,k,i]-m2[n,k,j]) + b_rm[t] ) + A[t,i,j]
//   m1[n,(r,t'),v] = sum_c x[n,t',v,c]*w_m1[r,c] + b_m1[r]   (m2 likewise)
//   xf[n,t,v,o]    = sum_c x[n,t,v,c]*w_f[o,c] + b_f[o]
// N=T=V=C=OUT=64, RED=2, K=RED*T=128.
// 3-kernel plan, bf16 MFMA (16x16x32) for all three matmuls.
// ---------------------------------------------------------------------------

typedef float  f32x4  __attribute__((ext_vector_type(4)));
typedef short  bf16x8 __attribute__((ext_vector_type(8)));

static __device__ __forceinline__ short f2bf(float f) {
    unsigned u = __float_as_uint(f);
    unsigned r = (u + 0x7FFFu + ((u >> 16) & 1u)) >> 16;   // RNE
    return (short)r;
}

static __device__ __forceinline__ bf16x8 cvt8(const float* p) {
    float4 a = *(const float4*)p;
    float4 b = *(const float4*)(p + 4);
    bf16x8 r;
    r[0] = f2bf(a.x); r[1] = f2bf(a.y); r[2] = f2bf(a.z); r[3] = f2bf(a.w);
    r[4] = f2bf(b.x); r[5] = f2bf(b.y); r[6] = f2bf(b.z); r[7] = f2bf(b.w);
    return r;
}

#define MFMA16(a, b, c) __builtin_amdgcn_mfma_f32_16x16x32_bf16((a), (b), (c), 0, 0, 0)

// ---------------------------------------------------------------------------
// K0: per (n,t) block.  xfT[n,t,o,v] = (w_f @ x[n,t]^T) + b_f   (bf16)
//     m1g[n,i,k], m2g[n,j,k]  (f32, k = r*64 + t)
// ---------------------------------------------------------------------------
__global__ __launch_bounds__(256) void k0_proj(
    const float* __restrict__ x,
    const float* __restrict__ w_f,  const float* __restrict__ b_f,
    const float* __restrict__ w_m1, const float* __restrict__ b_m1,
    const float* __restrict__ w_m2, const float* __restrict__ b_m2,
    short* __restrict__ xfT, float* __restrict__ m1g, float* __restrict__ m2g)
{
    const int b   = blockIdx.x;        // b = n*64 + t
    const int n   = b >> 6;
    const int t   = b & 63;
    const int tid = threadIdx.x;
    const int l = tid & 63, w = tid >> 6;
    const int lr = l & 15, lg = l >> 4;
    const float* xt = x + ((size_t)b << 12);   // x[n,t,:,:]  (64x64 f32)

    // ---- Part A: xfT tile.  D[o][v], A = w_f (OxC), B[c][v] = x[v][c].
    bf16x8 afr[2];
#pragma unroll
    for (int ks = 0; ks < 2; ++ks)
        afr[ks] = cvt8(w_f + (w * 16 + lr) * 64 + ks * 32 + lg * 8);

    f32x4 acc[4];
#pragma unroll
    for (int nt = 0; nt < 4; ++nt) acc[nt] = (f32x4){0.f, 0.f, 0.f, 0.f};

#pragma unroll
    for (int ks = 0; ks < 2; ++ks) {
#pragma unroll
        for (int nt = 0; nt < 4; ++nt) {
            bf16x8 bf = cvt8(xt + (nt * 16 + lr) * 64 + ks * 32 + lg * 8);
            acc[nt] = MFMA16(afr[ks], bf, acc[nt]);
        }
    }
    short* xo = xfT + ((size_t)b << 12);
#pragma unroll
    for (int nt = 0; nt < 4; ++nt) {
#pragma unroll
        for (int e = 0; e < 4; ++e) {
            int o = w * 16 + lg * 4 + e;      // C/D row = (l>>4)*4 + e
            int v = nt * 16 + lr;             // C/D col = l&15
            xo[o * 64 + v] = f2bf(acc[nt][e] + b_f[o]);
        }
    }

    // ---- Part B: m1/m2 projections. thread: i = tid&63, sel = tid>>6.
    {
        const int i   = tid & 63;
        const int sel = tid >> 6;             // 0:m1r0 1:m1r1 2:m2r0 3:m2r1
        const int r   = sel & 1;
        const float* wv = (sel < 2) ? (w_m1 + r * 64) : (w_m2 + r * 64);
        float a = (sel < 2) ? b_m1[r] : b_m2[r];
        const float4* xr = (const float4*)(xt + i * 64);
        const float4* wr = (const float4*)wv;
#pragma unroll
        for (int c = 0; c < 16; ++c) {
            float4 xv = xr[c], wq = wr[c];
            a += xv.x * wq.x + xv.y * wq.y + xv.z * wq.z + xv.w * wq.w;
        }
        float* dst = ((sel < 2) ? m1g : m2g) + n * 8192 + i * 128 + r * 64 + t;
        *dst = a;
    }
}

// ---------------------------------------------------------------------------
// K1: per (n, i-chunk of 4).  adjf[n,t,i,j] (bf16) for all t, j.
//     adj = w_rm (64x128) @ X (128 x [4i x 64j]),  X built on the fly (tanh).
// ---------------------------------------------------------------------------
__global__ __launch_bounds__(256) void k1_adj(
    const float* __restrict__ Ast,            // A (T,V,V)
    const float* __restrict__ w_rm, const float* __restrict__ b_rm,
    const float* __restrict__ m1g,  const float* __restrict__ m2g,
    const int* __restrict__ alpha_p,
    short* __restrict__ adjf)
{
    __shared__ float m2s[64 * 132];           // row-padded (+4 f32) vs bank conflicts
    __shared__ float m1s[4 * 128];

    const int b  = blockIdx.x;                // b = n*16 + ic
    const int n  = b >> 4;
    const int i0 = (b & 15) * 4;
    const int tid = threadIdx.x;

    // stage m2[n] (64x128 f32) and m1[n, i0..i0+3, :]
    const float4* src2 = (const float4*)(m2g + n * 8192);
    for (int it = tid; it < 2048; it += 256) {
        int j = it >> 5, q = it & 31;
        *((float4*)(m2s + j * 132) + q) = src2[it];
    }
    if (tid < 128) {
        const float4* src1 = (const float4*)(m1g + n * 8192 + i0 * 128);
        ((float4*)m1s)[tid] = src1[tid];
    }
    __syncthreads();

    const int l = tid & 63, w = tid >> 6;
    const int lr = l & 15, lg = l >> 4;
    const int ig = i0 + w;                    // this wave's global i

    float alpha;
    {   // alpha_m is a python scalar; robust to int32 or f32 encoding
        int raw = alpha_p[0];
        unsigned ur = (unsigned)(raw < 0 ? -raw : raw);
        alpha = (ur < (1u << 23)) ? (float)raw : __int_as_float(raw);
    }

    // hoist A-fragments: w_rm rows t = mt*16+lr, k contiguous 8
    bf16x8 afr[4][4];
#pragma unroll
    for (int mt = 0; mt < 4; ++mt)
#pragma unroll
        for (int kt = 0; kt < 4; ++kt)
            afr[mt][kt] = cvt8(w_rm + (mt * 16 + lr) * 128 + kt * 32 + lg * 8);

    const float* m1row = m1s + w * 128;

    for (int jt = 0; jt < 4; ++jt) {
        const int j = jt * 16 + lr;
        const float* m2row = m2s + j * 132;

        bf16x8 bfr[4];
#pragma unroll
        for (int kt = 0; kt < 4; ++kt) {
            const int k0 = kt * 32 + lg * 8;
            float4 a0 = *(const float4*)(m1row + k0);
            float4 a1 = *(const float4*)(m1row + k0 + 4);
            float4 b0 = *(const float4*)(m2row + k0);
            float4 b1 = *(const float4*)(m2row + k0 + 4);
            bfr[kt][0] = f2bf(tanhf(a0.x - b0.x));
            bfr[kt][1] = f2bf(tanhf(a0.y - b0.y));
            bfr[kt][2] = f2bf(tanhf(a0.z - b0.z));
            bfr[kt][3] = f2bf(tanhf(a0.w - b0.w));
            bfr[kt][4] = f2bf(tanhf(a1.x - b1.x));
            bfr[kt][5] = f2bf(tanhf(a1.y - b1.y));
            bfr[kt][6] = f2bf(tanhf(a1.z - b1.z));
            bfr[kt][7] = f2bf(tanhf(a1.w - b1.w));
        }

        f32x4 acc[4];
#pragma unroll
        for (int mt = 0; mt < 4; ++mt) acc[mt] = (f32x4){0.f, 0.f, 0.f, 0.f};
#pragma unroll
        for (int kt = 0; kt < 4; ++kt)
#pragma unroll
            for (int mt = 0; mt < 4; ++mt)
                acc[mt] = MFMA16(afr[mt][kt], bfr[kt], acc[mt]);

        // epilogue: adjf = alpha*(acc + b_rm[t]) + A[t,i,j]
        short* base = adjf + (((size_t)n) << 18) + ((size_t)(ig << 6)) + j;
#pragma unroll
        for (int mt = 0; mt < 4; ++mt) {
#pragma unroll
            for (int e = 0; e < 4; ++e) {
                int t = mt * 16 + lg * 4 + e;
                float val = alpha * (acc[mt][e] + b_rm[t])
                          + Ast[(t << 12) + (ig << 6) + j];
                base[(size_t)t << 12] = f2bf(val);
            }
        }
    }
}

// ---------------------------------------------------------------------------
// K2: batched out[n,t] = adjf[n,t] (64x64) @ xf[n,t] (64x64), f32 out.
//     One wave per (n,t); B-fragments read from transposed xfT (contiguous j).
// ---------------------------------------------------------------------------
__global__ __launch_bounds__(256) void k2_out(
    const short* __restrict__ adjf, const short* __restrict__ xfT,
    float* __restrict__ out)
{
    const int tid = threadIdx.x;
    const int l = tid & 63, w = tid >> 6;
    const int lr = l & 15, lg = l >> 4;
    const int pair = blockIdx.x * 4 + w;      // n*64 + t

    const short* Ab = adjf + ((size_t)pair << 12);
    const short* Bb = xfT  + ((size_t)pair << 12);
    float*       Ob = out  + ((size_t)pair << 12);

    bf16x8 af[4][2], bf[4][2];
#pragma unroll
    for (int mt = 0; mt < 4; ++mt)
#pragma unroll
        for (int ks = 0; ks < 2; ++ks)
            af[mt][ks] = *(const bf16x8*)(Ab + (mt * 16 + lr) * 64 + ks * 32 + lg * 8);
#pragma unroll
    for (int nt = 0; nt < 4; ++nt)
#pragma unroll
        for (int ks = 0; ks < 2; ++ks)
            bf[nt][ks] = *(const bf16x8*)(Bb + (nt * 16 + lr) * 64 + ks * 32 + lg * 8);

    f32x4 acc[4][4];
#pragma unroll
    for (int mt = 0; mt < 4; ++mt)
#pragma unroll
        for (int nt = 0; nt < 4; ++nt) acc[mt][nt] = (f32x4){0.f, 0.f, 0.f, 0.f};

#pragma unroll
    for (int ks = 0; ks < 2; ++ks)
#pragma unroll
        for (int mt = 0; mt < 4; ++mt)
#pragma unroll
            for (int nt = 0; nt < 4; ++nt)
                acc[mt][nt] = MFMA16(af[mt][ks], bf[nt][ks], acc[mt][nt]);

#pragma unroll
    for (int mt = 0; mt < 4; ++mt)
#pragma unroll
        for (int nt = 0; nt < 4; ++nt)
#pragma unroll
            for (int e = 0; e < 4; ++e) {
                int i = mt * 16 + lg * 4 + e;
                int o = nt * 16 + lr;
                Ob[i * 64 + o] = acc[mt][nt][e];
            }
}

// ---------------------------------------------------------------------------
extern "C" void kernel_launch(void* const* d_in, const int* in_sizes, int n_in,
                              void* d_out, int out_size, void* d_ws, size_t ws_size,
                              hipStream_t stream)
{
    const float* x    = (const float*)d_in[0];
    const float* A    = (const float*)d_in[1];
    const float* w_m1 = (const float*)d_in[2];
    const float* b_m1 = (const float*)d_in[3];
    const float* w_m2 = (const float*)d_in[4];
    const float* b_m2 = (const float*)d_in[5];
    const float* w_rm = (const float*)d_in[6];
    const float* b_rm = (const float*)d_in[7];
    const float* w_f  = (const float*)d_in[8];
    const float* b_f  = (const float*)d_in[9];
    const int*   alpha = (const int*)d_in[10];

    char* ws = (char*)d_ws;
    float* m1g = (float*)(ws);                              // 2 MB  [n][i][k]
    float* m2g = (float*)(ws + (size_t)2 * 1024 * 1024);    // 2 MB  [n][j][k]
    short* xfT = (short*)(ws + (size_t)4 * 1024 * 1024);    // 32 MB [n][t][o][v] bf16
    short* adjf = (short*)(ws + (size_t)4 * 1024 * 1024 + (size_t)33554432); // 32 MB bf16
    float* out = (float*)d_out;

    k0_proj<<<dim3(4096), dim3(256), 0, stream>>>(x, w_f, b_f, w_m1, b_m1,
                                                  w_m2, b_m2, xfT, m1g, m2g);
    k1_adj<<<dim3(1024), dim3(256), 0, stream>>>(A, w_rm, b_rm, m1g, m2g,
                                                 alpha, adjf);
    k2_out<<<dim3(1024), dim3(256), 0, stream>>>(adjf, xfT, out);
}

// Round 4
// 116.488 us; speedup vs baseline: 1.3409x; 1.3409x over previous
//
#include <hip/hip_runtime.h>

// ---------------------------------------------------------------------------
// DSTDGC: out[n,t,i,o] = sum_j adjf[n,t,i,j] * xf[n,t,j,o]
//   adjf = alpha*( sum_k w_rm[t,k]*tanh(m1[n,k,i]-m2[n,k,j]) + b_rm[t] ) + A[t,i,j]
//   m{1,2}[n,k=(r*64+t'),v] = sum_c x[n,t',v,c]*w_m{1,2}[r,c] + b_m{1,2}[r]
//   xf[n,t,v,o] = sum_c x[n,t,v,c]*w_f[o,c] + b_f[o]
// N=T=V=C=OUT=64, RED=2, K=128.  All stores vectorized+coalesced this round.
// (2nd resubmission — rounds 2 and 3 both died to an unresponsive MI355X
//  container before the kernel was ever compiled or run.)
// ---------------------------------------------------------------------------

typedef float  f32x4  __attribute__((ext_vector_type(4)));
typedef short  bf16x8 __attribute__((ext_vector_type(8)));
typedef short  bf16x4 __attribute__((ext_vector_type(4)));

static __device__ __forceinline__ short f2bf(float f) {
    unsigned u = __float_as_uint(f);
    unsigned r = (u + 0x7FFFu + ((u >> 16) & 1u)) >> 16;   // RNE
    return (short)r;
}

static __device__ __forceinline__ bf16x8 cvt8(const float* p) {
    float4 a = *(const float4*)p;
    float4 b = *(const float4*)(p + 4);
    bf16x8 r;
    r[0] = f2bf(a.x); r[1] = f2bf(a.y); r[2] = f2bf(a.z); r[3] = f2bf(a.w);
    r[4] = f2bf(b.x); r[5] = f2bf(b.y); r[6] = f2bf(b.z); r[7] = f2bf(b.w);
    return r;
}

// tanh(x) = 1 - 2/(exp(2x)+1); v_exp + v_rcp, correct at +-inf saturation.
static __device__ __forceinline__ float tanh_fast(float x) {
    float e = __expf(2.0f * x);
    return 1.0f - 2.0f * __builtin_amdgcn_rcpf(e + 1.0f);
}

#define MFMA16(a, b, c) __builtin_amdgcn_mfma_f32_16x16x32_bf16((a), (b), (c), 0, 0, 0)

// ---------------------------------------------------------------------------
// K0: per (n,t) block.  xfT[n,t,o,v] bf16 ; m1g/m2g[n][k][i] f32 (coalesced).
// Wave w computes o-rows w*16..w*16+15; wave 0 additionally computes the
// m1/m2 projections as a 5th (partially valid) A-tile of the same GEMM.
// All global stores staged through LDS -> 16B/lane contiguous.
// ---------------------------------------------------------------------------
__global__ __launch_bounds__(256) void k0_proj(
    const float* __restrict__ x,
    const float* __restrict__ w_f,  const float* __restrict__ b_f,
    const float* __restrict__ w_m1, const float* __restrict__ b_m1,
    const float* __restrict__ w_m2, const float* __restrict__ b_m2,
    short* __restrict__ xfT, float* __restrict__ m1g, float* __restrict__ m2g)
{
    __shared__ short xfs[64 * 72];      // [o][v] bf16, row-padded to 144B
    __shared__ float ms[4 * 64];        // [r'][v]  r'=0,1 -> m1 r; 2,3 -> m2 r

    const int b   = blockIdx.x;         // n*64 + t
    const int n   = b >> 6;
    const int t   = b & 63;
    const int tid = threadIdx.x;
    const int l = tid & 63, w = tid >> 6;
    const int lr = l & 15, lg = l >> 4;
    const float* xt = x + ((size_t)b << 12);

    // B-fragments: x rows v, contiguous c (each wave keeps all 8 in regs).
    bf16x8 bfrag[2][4];
#pragma unroll
    for (int ks = 0; ks < 2; ++ks)
#pragma unroll
        for (int nt = 0; nt < 4; ++nt)
            bfrag[ks][nt] = cvt8(xt + (nt * 16 + lr) * 64 + ks * 32 + lg * 8);

    // ---- xf tile for this wave's o-rows
    {
        bf16x8 afr[2];
#pragma unroll
        for (int ks = 0; ks < 2; ++ks)
            afr[ks] = cvt8(w_f + (w * 16 + lr) * 64 + ks * 32 + lg * 8);

        f32x4 acc[4];
#pragma unroll
        for (int nt = 0; nt < 4; ++nt) acc[nt] = (f32x4){0.f, 0.f, 0.f, 0.f};
#pragma unroll
        for (int ks = 0; ks < 2; ++ks)
#pragma unroll
            for (int nt = 0; nt < 4; ++nt)
                acc[nt] = MFMA16(afr[ks], bfrag[ks][nt], acc[nt]);

        // frag -> LDS (bias fused).  row o = w*16+lg*4+e, col v = nt*16+lr.
#pragma unroll
        for (int e = 0; e < 4; ++e) {
            int o = w * 16 + lg * 4 + e;
            float bo = b_f[o];
#pragma unroll
            for (int nt = 0; nt < 4; ++nt)
                xfs[o * 72 + nt * 16 + lr] = f2bf(acc[nt][e] + bo);
        }
    }

    // ---- m1/m2 tile (wave 0 only): A rows 0,1 = w_m1; 2,3 = w_m2; rest 0.
    if (w == 0) {
        bf16x8 amf[2];
#pragma unroll
        for (int ks = 0; ks < 2; ++ks) {
            bf16x8 z = {0, 0, 0, 0, 0, 0, 0, 0};
            if (lr < 4) {
                const float* wp = (lr < 2) ? (w_m1 + lr * 64)
                                           : (w_m2 + (lr - 2) * 64);
                z = cvt8(wp + ks * 32 + lg * 8);
            }
            amf[ks] = z;
        }
        f32x4 acc2[4];
#pragma unroll
        for (int nt = 0; nt < 4; ++nt) acc2[nt] = (f32x4){0.f, 0.f, 0.f, 0.f};
#pragma unroll
        for (int ks = 0; ks < 2; ++ks)
#pragma unroll
            for (int nt = 0; nt < 4; ++nt)
                acc2[nt] = MFMA16(amf[ks], bfrag[ks][nt], acc2[nt]);
        if (lg == 0) {                  // D rows 0..3 live in lg==0, e=0..3
#pragma unroll
            for (int e = 0; e < 4; ++e)
#pragma unroll
                for (int nt = 0; nt < 4; ++nt)
                    ms[e * 64 + nt * 16 + lr] = acc2[nt][e];
        }
    }
    __syncthreads();

    // ---- coalesced stores
    short* xo = xfT + ((size_t)b << 12);
#pragma unroll
    for (int pass = 0; pass < 2; ++pass) {
        int row = ((pass << 8) + tid) >> 3;        // 0..63
        int v0  = (tid & 7) * 8;
        bf16x8 vv = *(const bf16x8*)(xfs + row * 72 + v0);
        *(bf16x8*)(xo + row * 64 + v0) = vv;       // 16B/lane, contiguous
    }
    if (tid < 64) {
        int rp = tid >> 4;                          // 0..3
        int q  = (tid & 15) * 4;
        float4 vq = *(const float4*)(ms + rp * 64 + q);
        float bias = (rp < 2) ? b_m1[rp] : b_m2[rp - 2];
        vq.x += bias; vq.y += bias; vq.z += bias; vq.w += bias;
        float* dst = ((rp < 2) ? m1g : m2g)
                   + n * 8192 + ((rp & 1) * 64 + t) * 64 + q;   // [n][k][i]
        *(float4*)dst = vq;
    }
}

// ---------------------------------------------------------------------------
// K1: block = (n, i-chunk of 8), 512 threads (8 waves, 1 i each).
//  m2[n] staged [k][j]->[j][k] transposed in LDS (stride 136 f32: 16B-aligned,
//  conflict-light).  MFMA operands swapped -> D[j][t]: lane holds 4 consecutive
//  j at fixed t -> 8B bf16x4 stores into adjf[n,t,i,j].
// ---------------------------------------------------------------------------
__global__ __launch_bounds__(512) void k1_adj(
    const float* __restrict__ Ast,
    const float* __restrict__ w_rm, const float* __restrict__ b_rm,
    const float* __restrict__ m1g,  const float* __restrict__ m2g,
    const int* __restrict__ alpha_p,
    short* __restrict__ adjf)
{
    __shared__ float m2s[64 * 136];     // [j][k]
    __shared__ float m1s[8 * 136];      // [iq][k]

    const int b   = blockIdx.x;         // n*8 + ic
    const int n   = b >> 3;
    const int i0  = (b & 7) * 8;
    const int tid = threadIdx.x;

    // stage m2[n]: global [k][j] coalesced float4 -> LDS transposed [j][k]
    const float4* src2 = (const float4*)(m2g + n * 8192);
    for (int it = tid; it < 2048; it += 512) {
        int k  = it >> 4;
        int j0 = (it & 15) * 4;
        float4 v = src2[it];
        m2s[(j0 + 0) * 136 + k] = v.x;
        m2s[(j0 + 1) * 136 + k] = v.y;
        m2s[(j0 + 2) * 136 + k] = v.z;
        m2s[(j0 + 3) * 136 + k] = v.w;
    }
    // stage m1 rows i0..i0+7: global [k][i] -> LDS [iq][k]
    if (tid < 256) {
        int k    = tid & 127;
        int half = tid >> 7;
        float4 v = *(const float4*)(m1g + n * 8192 + k * 64 + i0 + half * 4);
        m1s[(half * 4 + 0) * 136 + k] = v.x;
        m1s[(half * 4 + 1) * 136 + k] = v.y;
        m1s[(half * 4 + 2) * 136 + k] = v.z;
        m1s[(half * 4 + 3) * 136 + k] = v.w;
    }
    __syncthreads();

    const int l = tid & 63, w = tid >> 6;
    const int lr = l & 15, lg = l >> 4;
    const int ig = i0 + w;

    float alpha;
    {
        int raw = alpha_p[0];
        unsigned ur = (unsigned)(raw < 0 ? -raw : raw);
        alpha = (ur < (1u << 23)) ? (float)raw : __int_as_float(raw);
    }

    // hoisted w_rm fragments (used as B operand: cols t, contiguous k)
    bf16x8 afr[4][4];
#pragma unroll
    for (int tt = 0; tt < 4; ++tt)
#pragma unroll
        for (int kt = 0; kt < 4; ++kt)
            afr[tt][kt] = cvt8(w_rm + (tt * 16 + lr) * 128 + kt * 32 + lg * 8);

    const float* m1row = m1s + w * 136;

    for (int jt = 0; jt < 4; ++jt) {
        const float* m2row = m2s + (jt * 16 + lr) * 136;

        bf16x8 bfr[4];                  // A operand: rows j, contiguous k
#pragma unroll
        for (int kt = 0; kt < 4; ++kt) {
            const int k0 = kt * 32 + lg * 8;
            float4 a0 = *(const float4*)(m1row + k0);
            float4 a1 = *(const float4*)(m1row + k0 + 4);
            float4 b0 = *(const float4*)(m2row + k0);
            float4 b1 = *(const float4*)(m2row + k0 + 4);
            bfr[kt][0] = f2bf(tanh_fast(a0.x - b0.x));
            bfr[kt][1] = f2bf(tanh_fast(a0.y - b0.y));
            bfr[kt][2] = f2bf(tanh_fast(a0.z - b0.z));
            bfr[kt][3] = f2bf(tanh_fast(a0.w - b0.w));
            bfr[kt][4] = f2bf(tanh_fast(a1.x - b1.x));
            bfr[kt][5] = f2bf(tanh_fast(a1.y - b1.y));
            bfr[kt][6] = f2bf(tanh_fast(a1.z - b1.z));
            bfr[kt][7] = f2bf(tanh_fast(a1.w - b1.w));
        }

        f32x4 acc[4];
#pragma unroll
        for (int tt = 0; tt < 4; ++tt) acc[tt] = (f32x4){0.f, 0.f, 0.f, 0.f};
#pragma unroll
        for (int kt = 0; kt < 4; ++kt)
#pragma unroll
            for (int tt = 0; tt < 4; ++tt)
                acc[tt] = MFMA16(bfr[kt], afr[tt][kt], acc[tt]);  // D[j][t]

        // lane: t = tt*16+lr, j = jt*16+lg*4+e (4 consecutive) -> 8B store
        const int j0 = jt * 16 + lg * 4;
#pragma unroll
        for (int tt = 0; tt < 4; ++tt) {
            int tq = tt * 16 + lr;
            float4 av = *(const float4*)(Ast + (tq << 12) + (ig << 6) + j0);
            float brm = b_rm[tq];
            bf16x4 pv;
            pv[0] = f2bf(alpha * (acc[tt][0] + brm) + av.x);
            pv[1] = f2bf(alpha * (acc[tt][1] + brm) + av.y);
            pv[2] = f2bf(alpha * (acc[tt][2] + brm) + av.z);
            pv[3] = f2bf(alpha * (acc[tt][3] + brm) + av.w);
            *(bf16x4*)(adjf + (((size_t)n) << 18) + ((size_t)tq << 12)
                       + (ig << 6) + j0) = pv;
        }
    }
}

// ---------------------------------------------------------------------------
// K2: one wave per (n,t): out[i,o] = sum_j adj[i,j] xf[j,o].
//  Operands swapped -> D[o][i]: lane holds 4 consecutive o at fixed i ->
//  float4 stores, 64B-coalesced per 4-lane group.
// ---------------------------------------------------------------------------
__global__ __launch_bounds__(256) void k2_out(
    const short* __restrict__ adjf, const short* __restrict__ xfT,
    float* __restrict__ out)
{
    const int tid = threadIdx.x;
    const int l = tid & 63, w = tid >> 6;
    const int lr = l & 15, lg = l >> 4;
    const int pair = blockIdx.x * 4 + w;      // n*64 + t

    const short* Ab = xfT  + ((size_t)pair << 12);  // A: rows o, contig j
    const short* Bb = adjf + ((size_t)pair << 12);  // B: cols i, contig j
    float*       Ob = out  + ((size_t)pair << 12);

    bf16x8 af[4][2], bf[4][2];
#pragma unroll
    for (int mt = 0; mt < 4; ++mt)
#pragma unroll
        for (int ks = 0; ks < 2; ++ks)
            af[mt][ks] = *(const bf16x8*)(Ab + (mt * 16 + lr) * 64 + ks * 32 + lg * 8);
#pragma unroll
    for (int nt = 0; nt < 4; ++nt)
#pragma unroll
        for (int ks = 0; ks < 2; ++ks)
            bf[nt][ks] = *(const bf16x8*)(Bb + (nt * 16 + lr) * 64 + ks * 32 + lg * 8);

    f32x4 acc[4][4];
#pragma unroll
    for (int mt = 0; mt < 4; ++mt)
#pragma unroll
        for (int nt = 0; nt < 4; ++nt) acc[mt][nt] = (f32x4){0.f, 0.f, 0.f, 0.f};

#pragma unroll
    for (int ks = 0; ks < 2; ++ks)
#pragma unroll
        for (int mt = 0; mt < 4; ++mt)
#pragma unroll
            for (int nt = 0; nt < 4; ++nt)
                acc[mt][nt] = MFMA16(af[mt][ks], bf[nt][ks], acc[mt][nt]);

    // D[o][i]: lane i = nt*16+lr (col), o = mt*16+lg*4+e (rows) -> float4
#pragma unroll
    for (int nt = 0; nt < 4; ++nt) {
        int i = nt * 16 + lr;
#pragma unroll
        for (int mt = 0; mt < 4; ++mt) {
            int o0 = mt * 16 + lg * 4;
            *(f32x4*)(Ob + i * 64 + o0) = acc[mt][nt];
        }
    }
}

// ---------------------------------------------------------------------------
extern "C" void kernel_launch(void* const* d_in, const int* in_sizes, int n_in,
                              void* d_out, int out_size, void* d_ws, size_t ws_size,
                              hipStream_t stream)
{
    const float* x    = (const float*)d_in[0];
    const float* A    = (const float*)d_in[1];
    const float* w_m1 = (const float*)d_in[2];
    const float* b_m1 = (const float*)d_in[3];
    const float* w_m2 = (const float*)d_in[4];
    const float* b_m2 = (const float*)d_in[5];
    const float* w_rm = (const float*)d_in[6];
    const float* b_rm = (const float*)d_in[7];
    const float* w_f  = (const float*)d_in[8];
    const float* b_f  = (const float*)d_in[9];
    const int*   alpha = (const int*)d_in[10];

    char* ws = (char*)d_ws;
    float* m1g = (float*)(ws);                              // 2 MB  [n][k][i]
    float* m2g = (float*)(ws + (size_t)2 * 1024 * 1024);    // 2 MB  [n][k][j]
    short* xfT = (short*)(ws + (size_t)4 * 1024 * 1024);    // 32 MB [n][t][o][v]
    short* adjf = (short*)(ws + (size_t)4 * 1024 * 1024 + (size_t)33554432);
    float* out = (float*)d_out;

    k0_proj<<<dim3(4096), dim3(256), 0, stream>>>(x, w_f, b_f, w_m1, b_m1,
                                                  w_m2, b_m2, xfT, m1g, m2g);
    k1_adj<<<dim3(512), dim3(512), 0, stream>>>(A, w_rm, b_rm, m1g, m2g,
                                                alpha, adjf);
    k2_out<<<dim3(1024), dim3(256), 0, stream>>>(adjf, xfT, out);
}

// Round 5
// 114.013 us; speedup vs baseline: 1.3700x; 1.0217x over previous
//
#include <hip/hip_runtime.h>

// ---------------------------------------------------------------------------
// DSTDGC: out[n,t,i,o] = sum_j adjf[n,t,i,j] * xf[n,t,j,o]
//   adjf = alpha*( sum_k w_rm[t,k]*tanh(m1[n,k,i]-m2[n,k,j]) + b_rm[t] ) + A[t,i,j]
// R5: K0 = 2 tiles/block (2x MLP).  K1+K2 fused into K12 (adj kept in LDS,
// no adjf global round-trip).  All stores vectorized+coalesced.
// ---------------------------------------------------------------------------

typedef float  f32x4  __attribute__((ext_vector_type(4)));
typedef short  bf16x8 __attribute__((ext_vector_type(8)));
typedef short  bf16x4 __attribute__((ext_vector_type(4)));

static __device__ __forceinline__ short f2bf(float f) {
    unsigned u = __float_as_uint(f);
    unsigned r = (u + 0x7FFFu + ((u >> 16) & 1u)) >> 16;   // RNE
    return (short)r;
}

static __device__ __forceinline__ bf16x8 cvt8(const float* p) {
    float4 a = *(const float4*)p;
    float4 b = *(const float4*)(p + 4);
    bf16x8 r;
    r[0] = f2bf(a.x); r[1] = f2bf(a.y); r[2] = f2bf(a.z); r[3] = f2bf(a.w);
    r[4] = f2bf(b.x); r[5] = f2bf(b.y); r[6] = f2bf(b.z); r[7] = f2bf(b.w);
    return r;
}

// tanh(x) = 1 - 2/(exp(2x)+1); v_exp + v_rcp, correct at +-inf saturation.
static __device__ __forceinline__ float tanh_fast(float x) {
    float e = __expf(2.0f * x);
    return 1.0f - 2.0f * __builtin_amdgcn_rcpf(e + 1.0f);
}

#define MFMA16(a, b, c) __builtin_amdgcn_mfma_f32_16x16x32_bf16((a), (b), (c), 0, 0, 0)

// ---------------------------------------------------------------------------
// K0: block = (n, t-pair).  Both tiles' x-loads issued up front (2x MLP).
//   xfT[n,t,o,v] bf16 ; m1g/m2g[n][k][i] f32.  Stores staged via LDS.
// ---------------------------------------------------------------------------
__global__ __launch_bounds__(256) void k0_proj(
    const float* __restrict__ x,
    const float* __restrict__ w_f,  const float* __restrict__ b_f,
    const float* __restrict__ w_m1, const float* __restrict__ b_m1,
    const float* __restrict__ w_m2, const float* __restrict__ b_m2,
    short* __restrict__ xfT, float* __restrict__ m1g, float* __restrict__ m2g)
{
    __shared__ short xfs[2][64 * 72];   // [tile][o][v] bf16, row-padded
    __shared__ float ms[2][4 * 64];     // [tile][r'][v]

    const int b   = blockIdx.x;         // n*32 + tp
    const int n   = b >> 5;
    const int tp  = b & 31;             // t = tp*2 + q
    const int tid = threadIdx.x;
    const int l = tid & 63, w = tid >> 6;
    const int lr = l & 15, lg = l >> 4;
    const float* xt0 = x + (((size_t)(n * 64 + tp * 2)) << 12);

    // weight fragments (shared by both tiles)
    bf16x8 afr[2];
#pragma unroll
    for (int ks = 0; ks < 2; ++ks)
        afr[ks] = cvt8(w_f + (w * 16 + lr) * 64 + ks * 32 + lg * 8);

    bf16x8 amf[2];
    if (w == 0) {
#pragma unroll
        for (int ks = 0; ks < 2; ++ks) {
            bf16x8 z = {0, 0, 0, 0, 0, 0, 0, 0};
            if (lr < 4) {
                const float* wp = (lr < 2) ? (w_m1 + lr * 64)
                                           : (w_m2 + (lr - 2) * 64);
                z = cvt8(wp + ks * 32 + lg * 8);
            }
            amf[ks] = z;
        }
    }

    // x fragments for BOTH tiles, loads issued together
    bf16x8 bfrag[2][2][4];              // [tile][ks][nt]
#pragma unroll
    for (int q = 0; q < 2; ++q)
#pragma unroll
        for (int ks = 0; ks < 2; ++ks)
#pragma unroll
            for (int nt = 0; nt < 4; ++nt)
                bfrag[q][ks][nt] =
                    cvt8(xt0 + q * 4096 + (nt * 16 + lr) * 64 + ks * 32 + lg * 8);

#pragma unroll
    for (int q = 0; q < 2; ++q) {
        f32x4 acc[4];
#pragma unroll
        for (int nt = 0; nt < 4; ++nt) acc[nt] = (f32x4){0.f, 0.f, 0.f, 0.f};
#pragma unroll
        for (int ks = 0; ks < 2; ++ks)
#pragma unroll
            for (int nt = 0; nt < 4; ++nt)
                acc[nt] = MFMA16(afr[ks], bfrag[q][ks][nt], acc[nt]);
#pragma unroll
        for (int e = 0; e < 4; ++e) {
            int o = w * 16 + lg * 4 + e;
            float bo = b_f[o];
#pragma unroll
            for (int nt = 0; nt < 4; ++nt)
                xfs[q][o * 72 + nt * 16 + lr] = f2bf(acc[nt][e] + bo);
        }
        if (w == 0) {
            f32x4 acc2[4];
#pragma unroll
            for (int nt = 0; nt < 4; ++nt) acc2[nt] = (f32x4){0.f, 0.f, 0.f, 0.f};
#pragma unroll
            for (int ks = 0; ks < 2; ++ks)
#pragma unroll
                for (int nt = 0; nt < 4; ++nt)
                    acc2[nt] = MFMA16(amf[ks], bfrag[q][ks][nt], acc2[nt]);
            if (lg == 0) {
#pragma unroll
                for (int e = 0; e < 4; ++e)
#pragma unroll
                    for (int nt = 0; nt < 4; ++nt)
                        ms[q][e * 64 + nt * 16 + lr] = acc2[nt][e];
            }
        }
    }
    __syncthreads();

    // coalesced stores, both tiles
    short* xo = xfT + (((size_t)(n * 64 + tp * 2)) << 12);
#pragma unroll
    for (int pass = 0; pass < 4; ++pass) {
        int idx = pass * 256 + tid;     // 0..1023
        int q   = idx >> 9;
        int row = (idx >> 3) & 63;
        int v0  = (idx & 7) * 8;
        *(bf16x8*)(xo + q * 4096 + row * 64 + v0) =
            *(const bf16x8*)(xfs[q] + row * 72 + v0);
    }
    if (tid < 128) {
        int q  = tid >> 6;
        int rp = (tid >> 4) & 3;
        int c4 = (tid & 15) * 4;
        float4 vq = *(const float4*)(ms[q] + rp * 64 + c4);
        float bias = (rp < 2) ? b_m1[rp] : b_m2[rp - 2];
        vq.x += bias; vq.y += bias; vq.z += bias; vq.w += bias;
        int t = tp * 2 + q;
        float* dst = ((rp < 2) ? m1g : m2g)
                   + n * 8192 + ((rp & 1) * 64 + t) * 64 + c4;  // [n][k][i]
        *(float4*)dst = vq;
    }
}

// ---------------------------------------------------------------------------
// K12: fused adj + PV.  Block = (n, i-chunk of 8), 512 threads (8 waves).
//  Phase A (== old K1): wave w owns i = i0+w; computes adj for all t,j and
//  writes bf16 into LDS adjs[t][w][j] (t-stride 584 shorts -> ~2-way banks).
//  Phase B: wave w owns t = w*8..w*8+7; per t computes
//  out[t,i0..i0+7,:] = adj_t(8i x 64j) @ xf_t(64j x 64o) via MFMA with
//  A = xf_t (M=o), B = adj (N=i, half-used).  float4 stores (64B segments).
// ---------------------------------------------------------------------------
__global__ __launch_bounds__(512) void k12_adj_out(
    const float* __restrict__ Ast,
    const float* __restrict__ w_rm, const float* __restrict__ b_rm,
    const float* __restrict__ m1g,  const float* __restrict__ m2g,
    const int* __restrict__ alpha_p,
    const short* __restrict__ xfT, float* __restrict__ out)
{
    __shared__ float m2s[64 * 136];             // [j][k]   34.8 KB
    __shared__ float m1s[8 * 136];              // [iq][k]   4.4 KB
    __shared__ short adjs[64 * 584 + 1024];     // [t][i][j] 76.8 KB (+OOB pad)

    // XCD-swizzle: co-locate the 8 i-chunk blocks of each n on one XCD
    // (xf_t re-reads then hit the same L2).  wgid = (n%8) + ic*8 + (n/8)*64.
    const int wg = blockIdx.x;
    const int n  = (wg & 7) + ((wg >> 6) << 3);
    const int i0 = ((wg >> 3) & 7) * 8;
    const int tid = threadIdx.x;

    // ---- stage m2[n] (transposed) and m1 rows i0..i0+7
    const float4* src2 = (const float4*)(m2g + n * 8192);
    for (int it = tid; it < 2048; it += 512) {
        int k  = it >> 4;
        int j0 = (it & 15) * 4;
        float4 v = src2[it];
        m2s[(j0 + 0) * 136 + k] = v.x;
        m2s[(j0 + 1) * 136 + k] = v.y;
        m2s[(j0 + 2) * 136 + k] = v.z;
        m2s[(j0 + 3) * 136 + k] = v.w;
    }
    if (tid < 256) {
        int k    = tid & 127;
        int half = tid >> 7;
        float4 v = *(const float4*)(m1g + n * 8192 + k * 64 + i0 + half * 4);
        m1s[(half * 4 + 0) * 136 + k] = v.x;
        m1s[(half * 4 + 1) * 136 + k] = v.y;
        m1s[(half * 4 + 2) * 136 + k] = v.z;
        m1s[(half * 4 + 3) * 136 + k] = v.w;
    }
    __syncthreads();

    const int l = tid & 63, w = tid >> 6;
    const int lr = l & 15, lg = l >> 4;
    const int ig = i0 + w;

    float alpha;
    {
        int raw = alpha_p[0];
        unsigned ur = (unsigned)(raw < 0 ? -raw : raw);
        alpha = (ur < (1u << 23)) ? (float)raw : __int_as_float(raw);
    }

    // ---- Phase A: adj rows for i = ig, all t, all j -> LDS
    {
        bf16x8 afr[4][4];               // w_rm fragments (B operand)
#pragma unroll
        for (int tt = 0; tt < 4; ++tt)
#pragma unroll
            for (int kt = 0; kt < 4; ++kt)
                afr[tt][kt] = cvt8(w_rm + (tt * 16 + lr) * 128 + kt * 32 + lg * 8);

        const float* m1row = m1s + w * 136;

        for (int jt = 0; jt < 4; ++jt) {
            const float* m2row = m2s + (jt * 16 + lr) * 136;

            bf16x8 bfr[4];              // A operand: rows j, contiguous k
#pragma unroll
            for (int kt = 0; kt < 4; ++kt) {
                const int k0 = kt * 32 + lg * 8;
                float4 a0 = *(const float4*)(m1row + k0);
                float4 a1 = *(const float4*)(m1row + k0 + 4);
                float4 b0 = *(const float4*)(m2row + k0);
                float4 b1 = *(const float4*)(m2row + k0 + 4);
                bfr[kt][0] = f2bf(tanh_fast(a0.x - b0.x));
                bfr[kt][1] = f2bf(tanh_fast(a0.y - b0.y));
                bfr[kt][2] = f2bf(tanh_fast(a0.z - b0.z));
                bfr[kt][3] = f2bf(tanh_fast(a0.w - b0.w));
                bfr[kt][4] = f2bf(tanh_fast(a1.x - b1.x));
                bfr[kt][5] = f2bf(tanh_fast(a1.y - b1.y));
                bfr[kt][6] = f2bf(tanh_fast(a1.z - b1.z));
                bfr[kt][7] = f2bf(tanh_fast(a1.w - b1.w));
            }

            f32x4 acc[4];
#pragma unroll
            for (int tt = 0; tt < 4; ++tt) acc[tt] = (f32x4){0.f, 0.f, 0.f, 0.f};
#pragma unroll
            for (int kt = 0; kt < 4; ++kt)
#pragma unroll
                for (int tt = 0; tt < 4; ++tt)
                    acc[tt] = MFMA16(bfr[kt], afr[tt][kt], acc[tt]);  // D[j][t]

            const int j0 = jt * 16 + lg * 4;
#pragma unroll
            for (int tt = 0; tt < 4; ++tt) {
                int tq = tt * 16 + lr;
                float4 av = *(const float4*)(Ast + (tq << 12) + (ig << 6) + j0);
                float brm = b_rm[tq];
                bf16x4 pv;
                pv[0] = f2bf(alpha * (acc[tt][0] + brm) + av.x);
                pv[1] = f2bf(alpha * (acc[tt][1] + brm) + av.y);
                pv[2] = f2bf(alpha * (acc[tt][2] + brm) + av.z);
                pv[3] = f2bf(alpha * (acc[tt][3] + brm) + av.w);
                *(bf16x4*)(adjs + tq * 584 + w * 72 + j0) = pv;   // 8B ds_write
            }
        }
    }
    __syncthreads();

    // ---- Phase B: wave w handles t = w*8 .. w*8+7
    const short* xn = xfT + (((size_t)n) << 18);
    float*       on = out + (((size_t)n) << 18);
#pragma unroll 2
    for (int tl = 0; tl < 8; ++tl) {
        const int t = w * 8 + tl;
        const short* xa = xn + ((size_t)t << 12);

        bf16x8 af[4][2];                // A = xf_t: rows o, contig j
#pragma unroll
        for (int mt = 0; mt < 4; ++mt)
#pragma unroll
            for (int ks = 0; ks < 2; ++ks)
                af[mt][ks] = *(const bf16x8*)(xa + (mt * 16 + lr) * 64
                                              + ks * 32 + lg * 8);
        bf16x8 bfv[2];                  // B = adj_t: col i=lr (lr<8 valid)
#pragma unroll
        for (int ks = 0; ks < 2; ++ks)
            bfv[ks] = *(const bf16x8*)(adjs + t * 584 + lr * 72
                                       + ks * 32 + lg * 8);

        f32x4 acc[4];
#pragma unroll
        for (int mt = 0; mt < 4; ++mt) acc[mt] = (f32x4){0.f, 0.f, 0.f, 0.f};
#pragma unroll
        for (int ks = 0; ks < 2; ++ks)
#pragma unroll
            for (int mt = 0; mt < 4; ++mt)
                acc[mt] = MFMA16(af[mt][ks], bfv[ks], acc[mt]);   // D[o][i]

        if (lr < 8) {                   // valid i columns only
            float* ob = on + ((size_t)t << 12) + (size_t)(i0 + lr) * 64;
#pragma unroll
            for (int mt = 0; mt < 4; ++mt)
                *(f32x4*)(ob + mt * 16 + lg * 4) = acc[mt];       // 16B store
        }
    }
}

// ---------------------------------------------------------------------------
extern "C" void kernel_launch(void* const* d_in, const int* in_sizes, int n_in,
                              void* d_out, int out_size, void* d_ws, size_t ws_size,
                              hipStream_t stream)
{
    const float* x    = (const float*)d_in[0];
    const float* A    = (const float*)d_in[1];
    const float* w_m1 = (const float*)d_in[2];
    const float* b_m1 = (const float*)d_in[3];
    const float* w_m2 = (const float*)d_in[4];
    const float* b_m2 = (const float*)d_in[5];
    const float* w_rm = (const float*)d_in[6];
    const float* b_rm = (const float*)d_in[7];
    const float* w_f  = (const float*)d_in[8];
    const float* b_f  = (const float*)d_in[9];
    const int*   alpha = (const int*)d_in[10];

    char* ws = (char*)d_ws;
    float* m1g = (float*)(ws);                              // 2 MB  [n][k][i]
    float* m2g = (float*)(ws + (size_t)2 * 1024 * 1024);    // 2 MB  [n][k][j]
    short* xfT = (short*)(ws + (size_t)4 * 1024 * 1024);    // 32 MB [n][t][o][v]
    float* out = (float*)d_out;

    k0_proj<<<dim3(2048), dim3(256), 0, stream>>>(x, w_f, b_f, w_m1, b_m1,
                                                  w_m2, b_m2, xfT, m1g, m2g);
    k12_adj_out<<<dim3(512), dim3(512), 0, stream>>>(A, w_rm, b_rm, m1g, m2g,
                                                     alpha, xfT, out);
}